// Round 1
// 976.904 us; speedup vs baseline: 1.0056x; 1.0056x over previous
//
#include <hip/hip_runtime.h>
#include <hip/hip_fp16.h>

#define T_TOK 8192
#define H_DIM 1024
#define E_NUM 8
#define I_DIM 1408

#define BM 128
#define BN 64
#define BK 32
#define LDA 40   // BK + 8 halves padding (80B rows: 16B-aligned, 2-way max conflict)
#define LDB 40

typedef __attribute__((ext_vector_type(8))) _Float16 half8;
typedef __attribute__((ext_vector_type(4))) _Float16 half4v;
typedef __attribute__((ext_vector_type(4))) float f32x4;

// ---------------- prep: x fp32 -> fp16 ----------------
__global__ __launch_bounds__(256) void xconv_kernel(
    const float* __restrict__ x, _Float16* __restrict__ xh)
{
    size_t i = ((size_t)blockIdx.x * 256 + threadIdx.x) * 4;
    float4 v = *(const float4*)(x + i);
    half4v hv = {(_Float16)v.x, (_Float16)v.y, (_Float16)v.z, (_Float16)v.w};
    *(half4v*)(xh + i) = hv;
}

// ---------------- prep: W fp32 [K][N] -> fp16 [N][K] (batched) ----------------
__global__ __launch_bounds__(256) void tconv_kernel(
    const float* __restrict__ src, _Float16* __restrict__ dst, int K, int N)
{
    __shared__ float tile[32][33];
    const size_t msz = (size_t)K * N;
    const float* s = src + (size_t)blockIdx.z * msz;
    _Float16*    d = dst + (size_t)blockIdx.z * msz;
    const int k0 = blockIdx.y * 32;
    const int n0 = blockIdx.x * 32;
    const int tid = threadIdx.x;
    {
        int r = tid >> 3, c = (tid & 7) * 4;
        float4 v = *(const float4*)(s + (size_t)(k0 + r) * N + n0 + c);
        tile[r][c] = v.x; tile[r][c+1] = v.y; tile[r][c+2] = v.z; tile[r][c+3] = v.w;
    }
    __syncthreads();
    {
        int n = tid >> 3, kq = (tid & 7) * 4;
        half4v hv = {(_Float16)tile[kq][n],   (_Float16)tile[kq+1][n],
                     (_Float16)tile[kq+2][n], (_Float16)tile[kq+3][n]};
        *(half4v*)(d + (size_t)(n0 + n) * K + k0 + kq) = hv;
    }
}

// ---------------- router: logits -> softmax -> top2 -> renorm ----------------
__global__ __launch_bounds__(64) void router_kernel(
    const float* __restrict__ x, const float* __restrict__ gw,
    int* __restrict__ cnt, int* __restrict__ tk_e, float* __restrict__ tk_w)
{
    const int t = blockIdx.x;
    const int lane = threadIdx.x;
    const float* xr = x + (size_t)t * H_DIM;
    float acc[8];
#pragma unroll
    for (int e = 0; e < 8; ++e) acc[e] = 0.f;
    for (int h = lane; h < H_DIM; h += 64) {
        float xv = xr[h];
        const float4* g4 = (const float4*)(gw + (size_t)h * 8);
        float4 ga = g4[0], gb = g4[1];
        acc[0] += xv * ga.x; acc[1] += xv * ga.y;
        acc[2] += xv * ga.z; acc[3] += xv * ga.w;
        acc[4] += xv * gb.x; acc[5] += xv * gb.y;
        acc[6] += xv * gb.z; acc[7] += xv * gb.w;
    }
#pragma unroll
    for (int e = 0; e < 8; ++e) {
#pragma unroll
        for (int off = 32; off > 0; off >>= 1)
            acc[e] += __shfl_xor(acc[e], off, 64);
    }
    if (lane == 0) {
        float mx = acc[0];
#pragma unroll
        for (int e = 1; e < 8; ++e) mx = fmaxf(mx, acc[e]);
        float p[8], sum = 0.f;
#pragma unroll
        for (int e = 0; e < 8; ++e) { p[e] = __expf(acc[e] - mx); sum += p[e]; }
        float inv = 1.f / sum;
#pragma unroll
        for (int e = 0; e < 8; ++e) p[e] *= inv;
        int e0 = 0;
#pragma unroll
        for (int e = 1; e < 8; ++e) if (p[e] > p[e0]) e0 = e;
        int e1 = (e0 == 0) ? 1 : 0;
#pragma unroll
        for (int e = 0; e < 8; ++e) if (e != e0 && p[e] > p[e1]) e1 = e;
        float w0 = p[e0], w1 = p[e1];
        float invw = 1.f / (w0 + w1 + 1e-6f);
        tk_e[2*t] = e0;      tk_e[2*t+1] = e1;
        tk_w[2*t] = w0*invw; tk_w[2*t+1] = w1*invw;
        atomicAdd(&cnt[e0], 1);
        atomicAdd(&cnt[e1], 1);
    }
}

// ---------------- tiny exclusive scan over 8 expert counts ----------------
__global__ void scan_kernel(const int* __restrict__ cnt, int* __restrict__ offs)
{
    if (threadIdx.x == 0) {
        int o = 0;
        for (int e = 0; e < 8; ++e) { offs[e] = o; o += cnt[e]; }
    }
}

// ---------------- scatter tokens into per-expert compact lists ----------------
__global__ __launch_bounds__(256) void scatter_kernel(
    const int* __restrict__ tk_e, const float* __restrict__ tk_w,
    const int* __restrict__ offs, int* __restrict__ fill,
    int* __restrict__ tokens, float* __restrict__ warr)
{
    int t = blockIdx.x * 256 + threadIdx.x;
    if (t >= T_TOK) return;
#pragma unroll
    for (int k = 0; k < 2; ++k) {
        int e = tk_e[2*t + k];
        int s = atomicAdd(&fill[e], 1);
        int idx = offs[e] + s;
        tokens[idx] = t;
        warr[idx]   = tk_w[2*t + k];
    }
}

// ---------------- GEMM1: h = silu(X Wg) * (X Wu), gathered rows ----------------
// all inputs pre-converted fp16; weights pre-transposed to [n=i][k=h]
__global__ __launch_bounds__(256) void gemm1_kernel(
    const _Float16* __restrict__ xh,
    const _Float16* __restrict__ egt, const _Float16* __restrict__ eut,
    const _Float16* __restrict__ sgt, const _Float16* __restrict__ sut,
    const int* __restrict__ cnt, const int* __restrict__ offs,
    const int* __restrict__ tokens, _Float16* __restrict__ hbuf)
{
    const int p = blockIdx.z;
    int count, rowbase;
    const _Float16 *Wg, *Wu;
    const int* tokptr = nullptr;
    if (p == 0) {
        count = T_TOK; rowbase = 0;
        Wg = sgt; Wu = sut;
    } else {
        int e = p - 1;
        count = cnt[e];
        int ob = offs[e];
        rowbase = T_TOK + ob;
        tokptr = tokens + ob;
        Wg = egt + (size_t)e * I_DIM * H_DIM;
        Wu = eut + (size_t)e * I_DIM * H_DIM;
    }
    const int m0 = blockIdx.y * BM;
    if (m0 >= count) return;
    const int n0 = blockIdx.x * BN;
    const int tid = threadIdx.x;

    __shared__ _Float16 Asm[BM * LDA];
    __shared__ _Float16 Bg_sm[BN * LDB];
    __shared__ _Float16 Bu_sm[BN * LDB];
    __shared__ int toksm[BM];

    if (tid < BM) {
        int s = m0 + tid;
        int t;
        if (p == 0) t = (s < count) ? s : 0;
        else        t = (s < count) ? tokptr[s] : 0;
        toksm[tid] = t;
    }
    __syncthreads();

    const int lane = tid & 63, wid = tid >> 6;
    const int wm = (wid >> 1) * 64, wn = (wid & 1) * 32;
    const int quad = lane >> 4, l16 = lane & 15;

    f32x4 zero4 = {0.f, 0.f, 0.f, 0.f};
    f32x4 accg[4][2], accu[4][2];
#pragma unroll
    for (int mt = 0; mt < 4; ++mt)
#pragma unroll
        for (int nt = 0; nt < 2; ++nt) { accg[mt][nt] = zero4; accu[mt][nt] = zero4; }

    for (int k0 = 0; k0 < H_DIM; k0 += BK) {
        // stage A (gathered fp16 X rows): 128 rows x 4 chunks of 8 halves (16B)
#pragma unroll
        for (int it = 0; it < 2; ++it) {
            int task = it * 256 + tid;
            int r = task >> 2;
            int c = (task & 3) * 8;
            int t = toksm[r];
            *(half8*)&Asm[r * LDA + c] =
                *(const half8*)(xh + (size_t)t * H_DIM + k0 + c);
        }
        // stage B (gate & up, pre-transposed [n][k] fp16): 64 n x 4 chunks of 8
        {
            int n = tid >> 2;
            int kg = (tid & 3) * 8;
            *(half8*)&Bg_sm[n * LDB + kg] =
                *(const half8*)(Wg + (size_t)(n0 + n) * H_DIM + k0 + kg);
            *(half8*)&Bu_sm[n * LDB + kg] =
                *(const half8*)(Wu + (size_t)(n0 + n) * H_DIM + k0 + kg);
        }
        __syncthreads();

        half8 a[4], bg[2], bu[2];
#pragma unroll
        for (int mt = 0; mt < 4; ++mt)
            a[mt] = *(const half8*)&Asm[(wm + mt*16 + l16) * LDA + quad * 8];
#pragma unroll
        for (int nt = 0; nt < 2; ++nt) {
            bg[nt] = *(const half8*)&Bg_sm[(wn + nt*16 + l16) * LDB + quad * 8];
            bu[nt] = *(const half8*)&Bu_sm[(wn + nt*16 + l16) * LDB + quad * 8];
        }
#pragma unroll
        for (int mt = 0; mt < 4; ++mt)
#pragma unroll
            for (int nt = 0; nt < 2; ++nt) {
                accg[mt][nt] = __builtin_amdgcn_mfma_f32_16x16x32_f16(a[mt], bg[nt], accg[mt][nt], 0, 0, 0);
                accu[mt][nt] = __builtin_amdgcn_mfma_f32_16x16x32_f16(a[mt], bu[nt], accu[mt][nt], 0, 0, 0);
            }
        __syncthreads();
    }

    // epilogue: h = silu(g)*u, store fp16 row-major [slot][I]
#pragma unroll
    for (int mt = 0; mt < 4; ++mt) {
#pragma unroll
        for (int nt = 0; nt < 2; ++nt) {
            int icol = n0 + wn + nt*16 + l16;
#pragma unroll
            for (int rg = 0; rg < 4; ++rg) {
                int s = m0 + wm + mt*16 + quad*4 + rg;
                if (s < count) {
                    float g = accg[mt][nt][rg];
                    float u = accu[mt][nt][rg];
                    float hval = (g / (1.f + __expf(-g))) * u;
                    hbuf[(size_t)(rowbase + s) * I_DIM + icol] = (_Float16)hval;
                }
            }
        }
    }
}

// ---------------- GEMM2: out[t] += w * (h Wd), atomic scatter-add ----------------
// down-proj weights pre-transposed to [n=h][k=i] fp16
__global__ __launch_bounds__(256) void gemm2_kernel(
    const _Float16* __restrict__ edt, const _Float16* __restrict__ sdt,
    const int* __restrict__ cnt, const int* __restrict__ offs,
    const int* __restrict__ tokens, const float* __restrict__ warr,
    const _Float16* __restrict__ hbuf, float* __restrict__ out)
{
    const int p = blockIdx.z;
    int count, rowbase;
    const _Float16* W;
    const int* tokptr = nullptr;
    const float* wptr = nullptr;
    if (p == 0) { count = T_TOK; rowbase = 0; W = sdt; }
    else {
        int e = p - 1;
        count = cnt[e];
        int ob = offs[e];
        rowbase = T_TOK + ob;
        tokptr = tokens + ob;
        wptr = warr + ob;
        W = edt + (size_t)e * H_DIM * I_DIM;
    }
    const int m0 = blockIdx.y * BM;
    if (m0 >= count) return;
    const int n0 = blockIdx.x * BN;
    const int tid = threadIdx.x;

    __shared__ _Float16 Asm[BM * LDA];
    __shared__ _Float16 Bsm[BN * LDB];
    __shared__ int toksm[BM];
    __shared__ float wsm[BM];

    if (tid < BM) {
        int s = m0 + tid;
        if (s < count) {
            toksm[tid] = p ? tokptr[s] : s;
            wsm[tid]   = p ? wptr[s]   : 1.f;
        } else { toksm[tid] = 0; wsm[tid] = 0.f; }
    }
    __syncthreads();

    const int lane = tid & 63, wid = tid >> 6;
    const int wm = (wid >> 1) * 64, wn = (wid & 1) * 32;
    const int quad = lane >> 4, l16 = lane & 15;

    f32x4 zero4 = {0.f, 0.f, 0.f, 0.f};
    f32x4 acc[4][2];
#pragma unroll
    for (int mt = 0; mt < 4; ++mt)
#pragma unroll
        for (int nt = 0; nt < 2; ++nt) acc[mt][nt] = zero4;

    for (int k0 = 0; k0 < I_DIM; k0 += BK) {
        // stage A from fp16 h buffer: 128 rows x 4 chunks of 8 halves (16B)
#pragma unroll
        for (int it = 0; it < 2; ++it) {
            int task = it * 256 + tid;
            int r = task >> 2;
            int c = (task & 3) * 8;
            int s = m0 + r;
            if (s < count) {
                *(int4*)&Asm[r * LDA + c] =
                    *(const int4*)&hbuf[(size_t)(rowbase + s) * I_DIM + k0 + c];
            } else {
                int4 z = {0, 0, 0, 0};
                *(int4*)&Asm[r * LDA + c] = z;
            }
        }
        // stage B (down-proj, pre-transposed [n][k] fp16)
        {
            int n = tid >> 2;
            int kg = (tid & 3) * 8;
            *(half8*)&Bsm[n * LDB + kg] =
                *(const half8*)(W + (size_t)(n0 + n) * I_DIM + k0 + kg);
        }
        __syncthreads();

        half8 a[4], b[2];
#pragma unroll
        for (int mt = 0; mt < 4; ++mt)
            a[mt] = *(const half8*)&Asm[(wm + mt*16 + l16) * LDA + quad * 8];
#pragma unroll
        for (int nt = 0; nt < 2; ++nt)
            b[nt] = *(const half8*)&Bsm[(wn + nt*16 + l16) * LDB + quad * 8];
#pragma unroll
        for (int mt = 0; mt < 4; ++mt)
#pragma unroll
            for (int nt = 0; nt < 2; ++nt)
                acc[mt][nt] = __builtin_amdgcn_mfma_f32_16x16x32_f16(a[mt], b[nt], acc[mt][nt], 0, 0, 0);
        __syncthreads();
    }

#pragma unroll
    for (int mt = 0; mt < 4; ++mt) {
#pragma unroll
        for (int nt = 0; nt < 2; ++nt) {
            int n = n0 + wn + nt*16 + l16;
#pragma unroll
            for (int rg = 0; rg < 4; ++rg) {
                int mloc = wm + mt*16 + quad*4 + rg;
                int s = m0 + mloc;
                if (s < count) {
                    int t = toksm[mloc];
                    float wgt = wsm[mloc];
                    atomicAdd(out + (size_t)t * H_DIM + n, wgt * acc[mt][nt][rg]);
                }
            }
        }
    }
}

// ---------------- launch ----------------
extern "C" void kernel_launch(void* const* d_in, const int* in_sizes, int n_in,
                              void* d_out, int out_size, void* d_ws, size_t ws_size,
                              hipStream_t stream)
{
    const float* x  = (const float*)d_in[0];
    const float* gw = (const float*)d_in[1];
    const float* eg = (const float*)d_in[2];
    const float* eu = (const float*)d_in[3];
    const float* ed = (const float*)d_in[4];
    const float* sg = (const float*)d_in[5];
    const float* su = (const float*)d_in[6];
    const float* sd = (const float*)d_in[7];
    float* out = (float*)d_out;

    char* ws = (char*)d_ws;
    int*   cnt    = (int*)(ws + 0);          // 8 ints
    int*   fill   = (int*)(ws + 32);         // 8 ints
    int*   offs   = (int*)(ws + 64);         // 8 ints
    int*   tk_e   = (int*)(ws + 128);        // 2T ints
    float* tk_w   = (float*)(ws + 128 + 65536);
    int*   tokens = (int*)(ws + 128 + 2*65536);
    float* warr   = (float*)(ws + 128 + 3*65536);

    _Float16* hbuf = (_Float16*)(ws + 524288);           // 3T x I fp16 ~ 69.2 MB
    _Float16* xh   = hbuf + (size_t)3 * T_TOK * I_DIM;   // T x H fp16 ~ 16.8 MB
    _Float16* egt  = xh  + (size_t)T_TOK * H_DIM;        // E x I x H fp16 ~ 23.1 MB
    _Float16* eut  = egt + (size_t)E_NUM * I_DIM * H_DIM;
    _Float16* edt  = eut + (size_t)E_NUM * I_DIM * H_DIM; // E x H x I fp16
    _Float16* sgt  = edt + (size_t)E_NUM * H_DIM * I_DIM; // I x H fp16
    _Float16* sut  = sgt + (size_t)I_DIM * H_DIM;
    _Float16* sdt  = sut + (size_t)I_DIM * H_DIM;         // H x I fp16
    (void)ws_size;

    hipMemsetAsync(d_out, 0, (size_t)out_size * sizeof(float), stream);
    hipMemsetAsync(ws, 0, 96, stream);

    // prep: fp16 conversion + weight transposition (loop-invariant work hoisted
    // out of the GEMM inner loops)
    xconv_kernel<<<(T_TOK * H_DIM) / 1024, 256, 0, stream>>>(x, xh);
    tconv_kernel<<<dim3(I_DIM/32, H_DIM/32, E_NUM), 256, 0, stream>>>(eg, egt, H_DIM, I_DIM);
    tconv_kernel<<<dim3(I_DIM/32, H_DIM/32, E_NUM), 256, 0, stream>>>(eu, eut, H_DIM, I_DIM);
    tconv_kernel<<<dim3(H_DIM/32, I_DIM/32, E_NUM), 256, 0, stream>>>(ed, edt, I_DIM, H_DIM);
    tconv_kernel<<<dim3(I_DIM/32, H_DIM/32, 1), 256, 0, stream>>>(sg, sgt, H_DIM, I_DIM);
    tconv_kernel<<<dim3(I_DIM/32, H_DIM/32, 1), 256, 0, stream>>>(su, sut, H_DIM, I_DIM);
    tconv_kernel<<<dim3(H_DIM/32, I_DIM/32, 1), 256, 0, stream>>>(sd, sdt, I_DIM, H_DIM);

    router_kernel<<<T_TOK, 64, 0, stream>>>(x, gw, cnt, tk_e, tk_w);
    scan_kernel<<<1, 64, 0, stream>>>(cnt, offs);
    scatter_kernel<<<T_TOK / 256, 256, 0, stream>>>(tk_e, tk_w, offs, fill, tokens, warr);
    gemm1_kernel<<<dim3(I_DIM / BN, T_TOK / BM, 9), 256, 0, stream>>>(
        xh, egt, eut, sgt, sut, cnt, offs, tokens, hbuf);
    gemm2_kernel<<<dim3(H_DIM / BN, T_TOK / BM, 9), 256, 0, stream>>>(
        edt, sdt, cnt, offs, tokens, warr, hbuf, out);
}

// Round 2
// 866.093 us; speedup vs baseline: 1.1343x; 1.1279x over previous
//
#include <hip/hip_runtime.h>
#include <hip/hip_fp16.h>

#define T_TOK 8192
#define H_DIM 1024
#define E_NUM 8
#define I_DIM 1408

#define BM 128
#define BN 64
#define BK 32
// LDS tiles are LINEAR (32 halves = 64B per row) for global_load_lds.
// Bank conflicts avoided via XOR chunk swizzle: chunk' = chunk ^ ((row>>1)&3),
// applied to BOTH the global source address and the ds_read address (rule #21).

typedef __attribute__((ext_vector_type(8))) _Float16 half8;
typedef __attribute__((ext_vector_type(4))) _Float16 half4v;
typedef __attribute__((ext_vector_type(4))) float f32x4;

__device__ __forceinline__ void gload_lds16(const void* g, void* l) {
    __builtin_amdgcn_global_load_lds(
        (const __attribute__((address_space(1))) unsigned int*)g,
        (__attribute__((address_space(3))) unsigned int*)l, 16, 0, 0);
}

// ---------------- prep: x fp32 -> fp16 ----------------
__global__ __launch_bounds__(256) void xconv_kernel(
    const float* __restrict__ x, _Float16* __restrict__ xh)
{
    size_t i = ((size_t)blockIdx.x * 256 + threadIdx.x) * 4;
    float4 v = *(const float4*)(x + i);
    half4v hv = {(_Float16)v.x, (_Float16)v.y, (_Float16)v.z, (_Float16)v.w};
    *(half4v*)(xh + i) = hv;
}

// ---------------- prep: W fp32 [K][N] -> fp16 [N][K] (batched) ----------------
__global__ __launch_bounds__(256) void tconv_kernel(
    const float* __restrict__ src, _Float16* __restrict__ dst, int K, int N)
{
    __shared__ float tile[32][33];
    const size_t msz = (size_t)K * N;
    const float* s = src + (size_t)blockIdx.z * msz;
    _Float16*    d = dst + (size_t)blockIdx.z * msz;
    const int k0 = blockIdx.y * 32;
    const int n0 = blockIdx.x * 32;
    const int tid = threadIdx.x;
    {
        int r = tid >> 3, c = (tid & 7) * 4;
        float4 v = *(const float4*)(s + (size_t)(k0 + r) * N + n0 + c);
        tile[r][c] = v.x; tile[r][c+1] = v.y; tile[r][c+2] = v.z; tile[r][c+3] = v.w;
    }
    __syncthreads();
    {
        int n = tid >> 3, kq = (tid & 7) * 4;
        half4v hv = {(_Float16)tile[kq][n],   (_Float16)tile[kq+1][n],
                     (_Float16)tile[kq+2][n], (_Float16)tile[kq+3][n]};
        *(half4v*)(d + (size_t)(n0 + n) * K + k0 + kq) = hv;
    }
}

// ---------------- router: logits -> softmax -> top2 -> renorm ----------------
__global__ __launch_bounds__(64) void router_kernel(
    const float* __restrict__ x, const float* __restrict__ gw,
    int* __restrict__ cnt, int* __restrict__ tk_e, float* __restrict__ tk_w)
{
    const int t = blockIdx.x;
    const int lane = threadIdx.x;
    const float* xr = x + (size_t)t * H_DIM;
    float acc[8];
#pragma unroll
    for (int e = 0; e < 8; ++e) acc[e] = 0.f;
    for (int h = lane; h < H_DIM; h += 64) {
        float xv = xr[h];
        const float4* g4 = (const float4*)(gw + (size_t)h * 8);
        float4 ga = g4[0], gb = g4[1];
        acc[0] += xv * ga.x; acc[1] += xv * ga.y;
        acc[2] += xv * ga.z; acc[3] += xv * ga.w;
        acc[4] += xv * gb.x; acc[5] += xv * gb.y;
        acc[6] += xv * gb.z; acc[7] += xv * gb.w;
    }
#pragma unroll
    for (int e = 0; e < 8; ++e) {
#pragma unroll
        for (int off = 32; off > 0; off >>= 1)
            acc[e] += __shfl_xor(acc[e], off, 64);
    }
    if (lane == 0) {
        float mx = acc[0];
#pragma unroll
        for (int e = 1; e < 8; ++e) mx = fmaxf(mx, acc[e]);
        float p[8], sum = 0.f;
#pragma unroll
        for (int e = 0; e < 8; ++e) { p[e] = __expf(acc[e] - mx); sum += p[e]; }
        float inv = 1.f / sum;
#pragma unroll
        for (int e = 0; e < 8; ++e) p[e] *= inv;
        int e0 = 0;
#pragma unroll
        for (int e = 1; e < 8; ++e) if (p[e] > p[e0]) e0 = e;
        int e1 = (e0 == 0) ? 1 : 0;
#pragma unroll
        for (int e = 0; e < 8; ++e) if (e != e0 && p[e] > p[e1]) e1 = e;
        float w0 = p[e0], w1 = p[e1];
        float invw = 1.f / (w0 + w1 + 1e-6f);
        tk_e[2*t] = e0;      tk_e[2*t+1] = e1;
        tk_w[2*t] = w0*invw; tk_w[2*t+1] = w1*invw;
        atomicAdd(&cnt[e0], 1);
        atomicAdd(&cnt[e1], 1);
    }
}

// ---------------- tiny exclusive scan over 8 expert counts ----------------
__global__ void scan_kernel(const int* __restrict__ cnt, int* __restrict__ offs)
{
    if (threadIdx.x == 0) {
        int o = 0;
        for (int e = 0; e < 8; ++e) { offs[e] = o; o += cnt[e]; }
    }
}

// ---------------- scatter tokens into per-expert compact lists ----------------
__global__ __launch_bounds__(256) void scatter_kernel(
    const int* __restrict__ tk_e, const float* __restrict__ tk_w,
    const int* __restrict__ offs, int* __restrict__ fill,
    int* __restrict__ tokens, float* __restrict__ warr)
{
    int t = blockIdx.x * 256 + threadIdx.x;
    if (t >= T_TOK) return;
#pragma unroll
    for (int k = 0; k < 2; ++k) {
        int e = tk_e[2*t + k];
        int s = atomicAdd(&fill[e], 1);
        int idx = offs[e] + s;
        tokens[idx] = t;
        warr[idx]   = tk_w[2*t + k];
    }
}

// ---------------- GEMM1: h = silu(X Wg) * (X Wu), gathered rows ----------------
__global__ __launch_bounds__(256) void gemm1_kernel(
    const _Float16* __restrict__ xh,
    const _Float16* __restrict__ egt, const _Float16* __restrict__ eut,
    const _Float16* __restrict__ sgt, const _Float16* __restrict__ sut,
    const int* __restrict__ cnt, const int* __restrict__ offs,
    const int* __restrict__ tokens, _Float16* __restrict__ hbuf)
{
    const int p = blockIdx.z;
    int count, rowbase;
    const _Float16 *Wg, *Wu;
    const int* tokptr = nullptr;
    if (p == 0) {
        count = T_TOK; rowbase = 0;
        Wg = sgt; Wu = sut;
    } else {
        int e = p - 1;
        count = cnt[e];
        int ob = offs[e];
        rowbase = T_TOK + ob;
        tokptr = tokens + ob;
        Wg = egt + (size_t)e * I_DIM * H_DIM;
        Wu = eut + (size_t)e * I_DIM * H_DIM;
    }
    const int m0 = blockIdx.y * BM;
    if (m0 >= count) return;
    const int n0 = blockIdx.x * BN;
    const int tid = threadIdx.x;

    __shared__ _Float16 Asm[BM * BK];     // 128 x 32 halves, linear
    __shared__ _Float16 Bg_sm[BN * BK];   // 64 x 32
    __shared__ _Float16 Bu_sm[BN * BK];
    __shared__ int toksm[BM];

    if (tid < BM) {
        int s = m0 + tid;
        int t;
        if (p == 0) t = (s < count) ? s : 0;
        else        t = (s < count) ? tokptr[s] : 0;
        toksm[tid] = t;
    }
    __syncthreads();

    const int lane = tid & 63, wid = tid >> 6;
    const int wm = (wid >> 1) * 64, wn = (wid & 1) * 32;
    const int quad = lane >> 4, l16 = lane & 15;

    // ---- staging geometry: 16B chunks; chunk index p = it*256 + tid ----
    // row r = p>>2, chunk-in-row c = p&3; source chunk = c ^ ((r>>1)&3)
    const int rq = tid >> 2;              // row handled by this thread (it=0)
    const int sc = (tid & 3) ^ ((rq >> 1) & 3);   // swizzled source chunk
    const _Float16* pA0 = xh + (size_t)toksm[rq]      * H_DIM + sc * 8;
    const _Float16* pA1 = xh + (size_t)toksm[rq + 64] * H_DIM + sc * 8;
    const _Float16* pBg = Wg + (size_t)(n0 + rq) * H_DIM + sc * 8;
    const _Float16* pBu = Wu + (size_t)(n0 + rq) * H_DIM + sc * 8;
    _Float16* ldsA0 = &Asm  [(wid * 64)       * 8];
    _Float16* ldsA1 = &Asm  [(256 + wid * 64) * 8];
    _Float16* ldsBg = &Bg_sm[(wid * 64)       * 8];
    _Float16* ldsBu = &Bu_sm[(wid * 64)       * 8];

    // ---- fragment read addresses (swizzled) ----
    const int rsw = (l16 >> 1) & 3;       // == (row>>1)&3 for row = 16*a + l16

    f32x4 zero4 = {0.f, 0.f, 0.f, 0.f};
    f32x4 accg[4][2], accu[4][2];
#pragma unroll
    for (int mt = 0; mt < 4; ++mt)
#pragma unroll
        for (int nt = 0; nt < 2; ++nt) { accg[mt][nt] = zero4; accu[mt][nt] = zero4; }

    for (int k0 = 0; k0 < H_DIM; k0 += BK) {
        gload_lds16(pA0, ldsA0);
        gload_lds16(pA1, ldsA1);
        gload_lds16(pBg, ldsBg);
        gload_lds16(pBu, ldsBu);
        pA0 += BK; pA1 += BK; pBg += BK; pBu += BK;
        __syncthreads();

        half8 a[4], bg[2], bu[2];
#pragma unroll
        for (int mt = 0; mt < 4; ++mt)
            a[mt] = *(const half8*)&Asm[(wm + mt*16 + l16) * BK + (quad ^ rsw) * 8];
#pragma unroll
        for (int nt = 0; nt < 2; ++nt) {
            bg[nt] = *(const half8*)&Bg_sm[(wn + nt*16 + l16) * BK + (quad ^ rsw) * 8];
            bu[nt] = *(const half8*)&Bu_sm[(wn + nt*16 + l16) * BK + (quad ^ rsw) * 8];
        }
#pragma unroll
        for (int mt = 0; mt < 4; ++mt)
#pragma unroll
            for (int nt = 0; nt < 2; ++nt) {
                accg[mt][nt] = __builtin_amdgcn_mfma_f32_16x16x32_f16(a[mt], bg[nt], accg[mt][nt], 0, 0, 0);
                accu[mt][nt] = __builtin_amdgcn_mfma_f32_16x16x32_f16(a[mt], bu[nt], accu[mt][nt], 0, 0, 0);
            }
        __syncthreads();
    }

    // epilogue: h = silu(g)*u, store fp16 row-major [slot][I]
#pragma unroll
    for (int mt = 0; mt < 4; ++mt) {
#pragma unroll
        for (int nt = 0; nt < 2; ++nt) {
            int icol = n0 + wn + nt*16 + l16;
#pragma unroll
            for (int rg = 0; rg < 4; ++rg) {
                int s = m0 + wm + mt*16 + quad*4 + rg;
                if (s < count) {
                    float g = accg[mt][nt][rg];
                    float u = accu[mt][nt][rg];
                    float hval = (g / (1.f + __expf(-g))) * u;
                    hbuf[(size_t)(rowbase + s) * I_DIM + icol] = (_Float16)hval;
                }
            }
        }
    }
}

// ---------------- GEMM2: out[t] += w * (h Wd), atomic scatter-add ----------------
__global__ __launch_bounds__(256) void gemm2_kernel(
    const _Float16* __restrict__ edt, const _Float16* __restrict__ sdt,
    const int* __restrict__ cnt, const int* __restrict__ offs,
    const int* __restrict__ tokens, const float* __restrict__ warr,
    const _Float16* __restrict__ hbuf, float* __restrict__ out)
{
    const int p = blockIdx.z;
    int count, rowbase;
    const _Float16* W;
    const int* tokptr = nullptr;
    const float* wptr = nullptr;
    if (p == 0) { count = T_TOK; rowbase = 0; W = sdt; }
    else {
        int e = p - 1;
        count = cnt[e];
        int ob = offs[e];
        rowbase = T_TOK + ob;
        tokptr = tokens + ob;
        wptr = warr + ob;
        W = edt + (size_t)e * H_DIM * I_DIM;
    }
    const int m0 = blockIdx.y * BM;
    if (m0 >= count) return;
    const int n0 = blockIdx.x * BN;
    const int tid = threadIdx.x;

    __shared__ _Float16 Asm[BM * BK];
    __shared__ _Float16 Bsm[BN * BK];
    __shared__ int toksm[BM];
    __shared__ float wsm[BM];

    if (tid < BM) {
        int s = m0 + tid;
        if (s < count) {
            toksm[tid] = p ? tokptr[s] : s;
            wsm[tid]   = p ? wptr[s]   : 1.f;
        } else { toksm[tid] = 0; wsm[tid] = 0.f; }
    }
    __syncthreads();

    const int lane = tid & 63, wid = tid >> 6;
    const int wm = (wid >> 1) * 64, wn = (wid & 1) * 32;
    const int quad = lane >> 4, l16 = lane & 15;

    const int rq = tid >> 2;
    const int sc = (tid & 3) ^ ((rq >> 1) & 3);
    int s0 = m0 + rq;       s0 = (s0 < count) ? s0 : count - 1;
    int s1 = m0 + 64 + rq;  s1 = (s1 < count) ? s1 : count - 1;
    const _Float16* pA0 = hbuf + (size_t)(rowbase + s0) * I_DIM + sc * 8;
    const _Float16* pA1 = hbuf + (size_t)(rowbase + s1) * I_DIM + sc * 8;
    const _Float16* pB  = W    + (size_t)(n0 + rq) * I_DIM + sc * 8;
    _Float16* ldsA0 = &Asm[(wid * 64)       * 8];
    _Float16* ldsA1 = &Asm[(256 + wid * 64) * 8];
    _Float16* ldsB  = &Bsm[(wid * 64)       * 8];

    const int rsw = (l16 >> 1) & 3;

    f32x4 zero4 = {0.f, 0.f, 0.f, 0.f};
    f32x4 acc[4][2];
#pragma unroll
    for (int mt = 0; mt < 4; ++mt)
#pragma unroll
        for (int nt = 0; nt < 2; ++nt) acc[mt][nt] = zero4;

    for (int k0 = 0; k0 < I_DIM; k0 += BK) {
        gload_lds16(pA0, ldsA0);
        gload_lds16(pA1, ldsA1);
        gload_lds16(pB,  ldsB);
        pA0 += BK; pA1 += BK; pB += BK;
        __syncthreads();

        half8 a[4], b[2];
#pragma unroll
        for (int mt = 0; mt < 4; ++mt)
            a[mt] = *(const half8*)&Asm[(wm + mt*16 + l16) * BK + (quad ^ rsw) * 8];
#pragma unroll
        for (int nt = 0; nt < 2; ++nt)
            b[nt] = *(const half8*)&Bsm[(wn + nt*16 + l16) * BK + (quad ^ rsw) * 8];
#pragma unroll
        for (int mt = 0; mt < 4; ++mt)
#pragma unroll
            for (int nt = 0; nt < 2; ++nt)
                acc[mt][nt] = __builtin_amdgcn_mfma_f32_16x16x32_f16(a[mt], b[nt], acc[mt][nt], 0, 0, 0);
        __syncthreads();
    }

#pragma unroll
    for (int mt = 0; mt < 4; ++mt) {
#pragma unroll
        for (int nt = 0; nt < 2; ++nt) {
            int n = n0 + wn + nt*16 + l16;
#pragma unroll
            for (int rg = 0; rg < 4; ++rg) {
                int mloc = wm + mt*16 + quad*4 + rg;
                int s = m0 + mloc;
                if (s < count) {
                    int t = toksm[mloc];
                    float wgt = wsm[mloc];
                    atomicAdd(out + (size_t)t * H_DIM + n, wgt * acc[mt][nt][rg]);
                }
            }
        }
    }
}

// ---------------- launch ----------------
extern "C" void kernel_launch(void* const* d_in, const int* in_sizes, int n_in,
                              void* d_out, int out_size, void* d_ws, size_t ws_size,
                              hipStream_t stream)
{
    const float* x  = (const float*)d_in[0];
    const float* gw = (const float*)d_in[1];
    const float* eg = (const float*)d_in[2];
    const float* eu = (const float*)d_in[3];
    const float* ed = (const float*)d_in[4];
    const float* sg = (const float*)d_in[5];
    const float* su = (const float*)d_in[6];
    const float* sd = (const float*)d_in[7];
    float* out = (float*)d_out;

    char* ws = (char*)d_ws;
    int*   cnt    = (int*)(ws + 0);          // 8 ints
    int*   fill   = (int*)(ws + 32);         // 8 ints
    int*   offs   = (int*)(ws + 64);         // 8 ints
    int*   tk_e   = (int*)(ws + 128);        // 2T ints
    float* tk_w   = (float*)(ws + 128 + 65536);
    int*   tokens = (int*)(ws + 128 + 2*65536);
    float* warr   = (float*)(ws + 128 + 3*65536);

    _Float16* hbuf = (_Float16*)(ws + 524288);           // 3T x I fp16 ~ 69.2 MB
    _Float16* xh   = hbuf + (size_t)3 * T_TOK * I_DIM;   // T x H fp16 ~ 16.8 MB
    _Float16* egt  = xh  + (size_t)T_TOK * H_DIM;        // E x I x H fp16 ~ 23.1 MB
    _Float16* eut  = egt + (size_t)E_NUM * I_DIM * H_DIM;
    _Float16* edt  = eut + (size_t)E_NUM * I_DIM * H_DIM; // E x H x I fp16
    _Float16* sgt  = edt + (size_t)E_NUM * H_DIM * I_DIM; // I x H fp16
    _Float16* sut  = sgt + (size_t)I_DIM * H_DIM;
    _Float16* sdt  = sut + (size_t)I_DIM * H_DIM;         // H x I fp16
    (void)ws_size;

    hipMemsetAsync(d_out, 0, (size_t)out_size * sizeof(float), stream);
    hipMemsetAsync(ws, 0, 96, stream);

    // prep: fp16 conversion + weight transposition
    xconv_kernel<<<(T_TOK * H_DIM) / 1024, 256, 0, stream>>>(x, xh);
    tconv_kernel<<<dim3(I_DIM/32, H_DIM/32, E_NUM), 256, 0, stream>>>(eg, egt, H_DIM, I_DIM);
    tconv_kernel<<<dim3(I_DIM/32, H_DIM/32, E_NUM), 256, 0, stream>>>(eu, eut, H_DIM, I_DIM);
    tconv_kernel<<<dim3(H_DIM/32, I_DIM/32, E_NUM), 256, 0, stream>>>(ed, edt, I_DIM, H_DIM);
    tconv_kernel<<<dim3(I_DIM/32, H_DIM/32, 1), 256, 0, stream>>>(sg, sgt, H_DIM, I_DIM);
    tconv_kernel<<<dim3(I_DIM/32, H_DIM/32, 1), 256, 0, stream>>>(su, sut, H_DIM, I_DIM);
    tconv_kernel<<<dim3(H_DIM/32, I_DIM/32, 1), 256, 0, stream>>>(sd, sdt, I_DIM, H_DIM);

    router_kernel<<<T_TOK, 64, 0, stream>>>(x, gw, cnt, tk_e, tk_w);
    scan_kernel<<<1, 64, 0, stream>>>(cnt, offs);
    scatter_kernel<<<T_TOK / 256, 256, 0, stream>>>(tk_e, tk_w, offs, fill, tokens, warr);
    gemm1_kernel<<<dim3(I_DIM / BN, T_TOK / BM, 9), 256, 0, stream>>>(
        xh, egt, eut, sgt, sut, cnt, offs, tokens, hbuf);
    gemm2_kernel<<<dim3(H_DIM / BN, T_TOK / BM, 9), 256, 0, stream>>>(
        edt, sdt, cnt, offs, tokens, warr, hbuf, out);
}